// Round 10
// baseline (369.661 us; speedup 1.0000x reference)
//
#include <hip/hip_runtime.h>
#include <hip/hip_bf16.h>
#include <math.h>

#define D 128
#define NUM_GRAPHS 64
#define CHUNK 8192          // edges per binning block
#define BUCK_SH 8           // bucket = col >> 8  (256 nodes per bucket)
#define BUCK_N 256
#define PSLICE 8            // pooling blocks per graph
#define PITCH 136           // LDS row pitch (bf16 elems) for aggmm tile

typedef __bf16 bf16x8 __attribute__((ext_vector_type(8)));
typedef __bf16 bf16x2 __attribute__((ext_vector_type(2)));
typedef float f32x4 __attribute__((ext_vector_type(4)));

// ---------------- generic scan helpers (for the bucket-chunk table) ----------------
__global__ void k_scan1(const int* __restrict__ in, int* __restrict__ outv,
                        int* __restrict__ bsum, int N) {
    __shared__ int lds[256];
    int t = threadIdx.x;
    int base = blockIdx.x * 1024 + t * 4;
    int v[4]; int local = 0;
#pragma unroll
    for (int j = 0; j < 4; j++) { v[j] = (base + j < N) ? in[base + j] : 0; local += v[j]; }
    lds[t] = local;
    __syncthreads();
    for (int off = 1; off < 256; off <<= 1) {
        int x = (t >= off) ? lds[t - off] : 0;
        __syncthreads();
        lds[t] += x;
        __syncthreads();
    }
    int excl = lds[t] - local;
    if (t == 255) bsum[blockIdx.x] = lds[255];
    int run = excl;
#pragma unroll
    for (int j = 0; j < 4; j++) { if (base + j < N) outv[base + j] = run; run += v[j]; }
}

__global__ void k_scan2(int* __restrict__ bsum, int nb) {
    __shared__ int lds[256];
    int t = threadIdx.x;
    int v = (t < nb) ? bsum[t] : 0;
    lds[t] = v;
    __syncthreads();
    for (int off = 1; off < 256; off <<= 1) {
        int x = (t >= off) ? lds[t - off] : 0;
        __syncthreads();
        lds[t] += x;
        __syncthreads();
    }
    if (t < nb) bsum[t] = lds[t] - v;
}

// ---------------- CSR build: two-level counting sort ----------------
__global__ void k_hist(const int* __restrict__ col, int* __restrict__ hist,
                       int nbuck, int nchunk, int E) {
    __shared__ int h[512];
    int tid = threadIdx.x;
    for (int b = tid; b < nbuck; b += 256) h[b] = 0;
    __syncthreads();
    int base = blockIdx.x * CHUNK;
    for (int i = tid; i < CHUNK; i += 256) {
        int e = base + i;
        if (e < E) atomicAdd(&h[col[e] >> BUCK_SH], 1);
    }
    __syncthreads();
    for (int b = tid; b < nbuck; b += 256) hist[b * nchunk + blockIdx.x] = h[b];
}

__global__ void k_bin(const int* __restrict__ ei, const int* __restrict__ histS,
                      const int* __restrict__ bsum2, int* __restrict__ bbuf,
                      int nbuck, int nchunk, int E) {
    __shared__ int cur[512];
    int tid = threadIdx.x;
    for (int b = tid; b < nbuck; b += 256) {
        int idx = b * nchunk + blockIdx.x;
        cur[b] = histS[idx] + bsum2[idx >> 10];
    }
    __syncthreads();
    int base = blockIdx.x * CHUNK;
    for (int i = tid; i < CHUNK; i += 256) {
        int e = base + i;
        if (e < E) {
            int r = ei[e], c = ei[E + e];
            int pos = atomicAdd(&cur[c >> BUCK_SH], 1);
            bbuf[pos] = r | ((c & (BUCK_N - 1)) << 17);   // src fits 17 bits (N < 131072)
        }
    }
}

// per-bucket exact CSR: LDS histogram + LDS scan + LDS cursors. No global atomics.
__global__ void k_place(const int* __restrict__ bbuf, const int* __restrict__ histS,
                        const int* __restrict__ bsum2, int* __restrict__ esrc,
                        int* __restrict__ cnt, int* __restrict__ offs,
                        float* __restrict__ dis,
                        int nbuck, int nchunk, int N, int E) {
    __shared__ int h[256];
    __shared__ int sc[256];
    __shared__ int cur[256];
    int b = blockIdx.x, tid = threadIdx.x;
    int i0 = b * nchunk;
    int start = histS[i0] + bsum2[i0 >> 10];
    int end = E;
    if (b + 1 < nbuck) { int i1 = (b + 1) * nchunk; end = histS[i1] + bsum2[i1 >> 10]; }
    h[tid] = 0;
    __syncthreads();
    for (int i = start + tid; i < end; i += 256) atomicAdd(&h[(bbuf[i] >> 17) & 255], 1);
    __syncthreads();
    int local = h[tid];
    sc[tid] = local;
    __syncthreads();
    for (int off = 1; off < 256; off <<= 1) {
        int xv = (tid >= off) ? sc[tid - off] : 0;
        __syncthreads();
        sc[tid] += xv;
        __syncthreads();
    }
    int excl = sc[tid] - local;
    cur[tid] = start + excl;
    int c = b * 256 + tid;
    if (c < N) {
        cnt[c]  = local;
        offs[c] = start + excl;
        dis[c]  = rsqrtf(1.0f + (float)local);   // deg includes self-loop
    }
    __syncthreads();
    for (int i = start + tid; i < end; i += 256) {
        int p = bbuf[i];
        int pos = atomicAdd(&cur[(p >> 17) & 255], 1);
        esrc[pos] = p & 0x1FFFF;
    }
}

// ---------------- W -> bf16 B-fragment pack; zero pooled/done; graph boundaries ----------------
__global__ void k_prepW(const float* __restrict__ Wa, const float* __restrict__ Wb,
                        __bf16* __restrict__ WfA, __bf16* __restrict__ WfB,
                        float* __restrict__ pooled, int* __restrict__ done,
                        const int* __restrict__ batch, int* __restrict__ gstart, int N) {
    int gid = blockIdx.x * 256 + threadIdx.x;   // 0..32767
    if (gid < NUM_GRAPHS * D) pooled[gid] = 0.f;
    if (gid == 0) *done = 0;
    if (gid >= 16384 && gid <= 16384 + NUM_GRAPHS) {   // 65 threads do binary search
        int g = gid - 16384;
        int lo = 0, hi = N;
        while (lo < hi) { int mid = (lo + hi) >> 1; if (batch[mid] < g) lo = mid + 1; else hi = mid; }
        gstart[g] = lo;
    }
    const float* W = (gid < 16384) ? Wa : Wb;
    __bf16* Wf = (gid < 16384) ? WfA : WfB;
    int idx = gid & 16383;
    int j = idx & 7, lane = (idx >> 3) & 63, kc = (idx >> 9) & 3, ft = idx >> 11;
    int k = kc * 32 + (lane >> 4) * 8 + j;
    int f = ft * 16 + (lane & 15);
    Wf[idx] = (__bf16)W[k * D + f];
}

// ---------------- MFMA GEMM: Y[N,128](bf16) = dis .* (X[N,128] @ W) ----------------
template <typename T>
__launch_bounds__(256)
__global__ void k_gemm(const T* __restrict__ X, const __bf16* __restrict__ Wfrag,
                       const float* __restrict__ dis, __bf16* __restrict__ Y, int N) {
    int tid = threadIdx.x;
    int w = tid >> 6, lane = tid & 63;
    int quad = lane >> 4, m = lane & 15;
    int nodeA = blockIdx.x * 64 + w * 16 + m;
    if (nodeA >= N) nodeA = N - 1;

    bf16x8 a[4];
#pragma unroll
    for (int kc = 0; kc < 4; kc++) {
        int kb = kc * 32 + quad * 8;
        if constexpr (sizeof(T) == 4) {
            f32x4 x0 = *(const f32x4*)(X + (size_t)nodeA * D + kb);
            f32x4 x1 = *(const f32x4*)(X + (size_t)nodeA * D + kb + 4);
#pragma unroll
            for (int j = 0; j < 4; j++) { a[kc][j] = (__bf16)x0[j]; a[kc][4 + j] = (__bf16)x1[j]; }
        } else {
            a[kc] = *(const bf16x8*)(X + (size_t)nodeA * D + kb);
        }
    }

    f32x4 d[8];
#pragma unroll
    for (int ft = 0; ft < 8; ft++) {
        d[ft] = (f32x4){0.f, 0.f, 0.f, 0.f};
#pragma unroll
        for (int kc = 0; kc < 4; kc++) {
            bf16x8 b = *(const bf16x8*)(Wfrag + (((ft << 2) | kc) * 64 + lane) * 8);
            d[ft] = __builtin_amdgcn_mfma_f32_16x16x32_bf16(a[kc], b, d[ft], 0, 0, 0);
        }
    }

#pragma unroll
    for (int r = 0; r < 4; r++) {
        int node = blockIdx.x * 64 + w * 16 + quad * 4 + r;
        if (node < N) {
            float dv = dis[node];
#pragma unroll
            for (int ft = 0; ft < 8; ft++)
                Y[(size_t)node * D + ft * 16 + m] = (__bf16)(d[ft][r] * dv);
        }
    }
}

// ---------------- fused agg(layer1) + GEMM(layer2): Y = dis .* (leaky(agg(Hs)+b) @ W) ----------------
// Wave processes 16 consecutive nodes: CSR gather-sum (Hs prescaled by dis) ->
// bias+leaky -> park in wave-private LDS tile (pitch 136 bf16) -> read MFMA
// A-fragments (bank-balanced ds_read_b128) -> 32 MFMAs vs L1-hot Wfrag ->
// dis-prescale epilogue -> store. No __syncthreads: LDS tile is wave-private.
__launch_bounds__(256)
__global__ void k_aggmm(const __bf16* __restrict__ Hs, const __bf16* __restrict__ Wfrag,
                        __bf16* __restrict__ Y,
                        const int* __restrict__ offs, const int* __restrict__ cnt,
                        const float* __restrict__ dis, const int* __restrict__ esrc,
                        const float* __restrict__ bias, int N) {
    __shared__ __bf16 sH[4][16 * PITCH];
    int tid = threadIdx.x;
    int w = tid >> 6, lane = tid & 63;
    int node0 = (blockIdx.x * 4 + w) * 16;
    float b0 = bias[lane * 2], b1 = bias[lane * 2 + 1];
    __bf16* my = &sH[w][0];

    for (int nn = 0; nn < 16; nn++) {
        int node = node0 + nn;
        float acc0 = 0.f, acc1 = 0.f;
        if (node < N) {
            int start = offs[node];
            int len = cnt[node];
            float di = dis[node];
            bf16x2 h = *(const bf16x2*)(Hs + (size_t)node * D + lane * 2);
            acc0 = (float)h[0];          // self-loop term (already dis-scaled)
            acc1 = (float)h[1];
            for (int k0 = 0; k0 < len; k0 += 64) {
                int mm = len - k0; if (mm > 64) mm = 64;
                int ep = esrc[start + k0 + (lane < mm ? lane : 0)];
                int j = 0;
                for (; j + 16 <= mm; j += 16) {
                    int s[16]; bf16x2 hv[16];
#pragma unroll
                    for (int u = 0; u < 16; u++) s[u] = __shfl(ep, j + u);
#pragma unroll
                    for (int u = 0; u < 16; u++) hv[u] = *(const bf16x2*)(Hs + (size_t)s[u] * D + lane * 2);
#pragma unroll
                    for (int u = 0; u < 16; u++) { acc0 += (float)hv[u][0]; acc1 += (float)hv[u][1]; }
                }
                for (; j + 4 <= mm; j += 4) {
                    int s[4]; bf16x2 hv[4];
#pragma unroll
                    for (int u = 0; u < 4; u++) s[u] = __shfl(ep, j + u);
#pragma unroll
                    for (int u = 0; u < 4; u++) hv[u] = *(const bf16x2*)(Hs + (size_t)s[u] * D + lane * 2);
#pragma unroll
                    for (int u = 0; u < 4; u++) { acc0 += (float)hv[u][0]; acc1 += (float)hv[u][1]; }
                }
                for (; j < mm; j++) {
                    int s = __shfl(ep, j);
                    bf16x2 hv = *(const bf16x2*)(Hs + (size_t)s * D + lane * 2);
                    acc0 += (float)hv[0]; acc1 += (float)hv[1];
                }
            }
            acc0 = acc0 * di + b0;
            acc1 = acc1 * di + b1;
            acc0 = acc0 >= 0.f ? acc0 : 0.01f * acc0;
            acc1 = acc1 >= 0.f ? acc1 : 0.01f * acc1;
        }
        bf16x2 o; o[0] = (__bf16)acc0; o[1] = (__bf16)acc1;
        *(bf16x2*)(my + nn * PITCH + lane * 2) = o;
    }

    // MFMA phase: lane (q=lane>>4, m=lane&15) holds A[m][kc*32+q*8 .. +7]
    int q = lane >> 4, m = lane & 15;
    bf16x8 a[4];
#pragma unroll
    for (int kc = 0; kc < 4; kc++)
        a[kc] = *(const bf16x8*)(my + m * PITCH + kc * 32 + q * 8);

    f32x4 d[8];
#pragma unroll
    for (int ft = 0; ft < 8; ft++) {
        d[ft] = (f32x4){0.f, 0.f, 0.f, 0.f};
#pragma unroll
        for (int kc = 0; kc < 4; kc++) {
            bf16x8 b = *(const bf16x8*)(Wfrag + (((ft << 2) | kc) * 64 + lane) * 8);
            d[ft] = __builtin_amdgcn_mfma_f32_16x16x32_bf16(a[kc], b, d[ft], 0, 0, 0);
        }
    }

#pragma unroll
    for (int r = 0; r < 4; r++) {
        int node = node0 + q * 4 + r;
        if (node < N) {
            float dv = dis[node];
#pragma unroll
            for (int ft = 0; ft < 8; ft++)
                Y[(size_t)node * D + ft * 16 + m] = (__bf16)(d[ft][r] * dv);
        }
    }
}

// ---------------- CSR aggregation + bias + leaky ReLU (layer 2; bf16 in/out) ----------------
__launch_bounds__(256)
__global__ void k_agg(const __bf16* __restrict__ Hs, __bf16* __restrict__ O,
                      const int* __restrict__ offs, const int* __restrict__ cnt,
                      const float* __restrict__ dis, const int* __restrict__ esrc,
                      const float* __restrict__ bias, int N) {
    int wave = (blockIdx.x * 256 + threadIdx.x) >> 6;
    int lane = threadIdx.x & 63;
    int node0 = wave * 8;
    float b0 = bias[lane * 2], b1 = bias[lane * 2 + 1];

    for (int nn = 0; nn < 8; nn++) {
        int node = node0 + nn;
        if (node >= N) return;
        int start = offs[node];
        int len = cnt[node];
        float di = dis[node];
        bf16x2 h = *(const bf16x2*)(Hs + (size_t)node * D + lane * 2);
        float acc0 = (float)h[0];            // self-loop term (already dis-scaled)
        float acc1 = (float)h[1];

        for (int k0 = 0; k0 < len; k0 += 64) {
            int mm = len - k0; if (mm > 64) mm = 64;
            int ep = esrc[start + k0 + (lane < mm ? lane : 0)];
            int j = 0;
            for (; j + 16 <= mm; j += 16) {
                int s[16]; bf16x2 hv[16];
#pragma unroll
                for (int u = 0; u < 16; u++) s[u] = __shfl(ep, j + u);
#pragma unroll
                for (int u = 0; u < 16; u++) hv[u] = *(const bf16x2*)(Hs + (size_t)s[u] * D + lane * 2);
#pragma unroll
                for (int u = 0; u < 16; u++) { acc0 += (float)hv[u][0]; acc1 += (float)hv[u][1]; }
            }
            for (; j + 4 <= mm; j += 4) {
                int s[4]; bf16x2 hv[4];
#pragma unroll
                for (int u = 0; u < 4; u++) s[u] = __shfl(ep, j + u);
#pragma unroll
                for (int u = 0; u < 4; u++) hv[u] = *(const bf16x2*)(Hs + (size_t)s[u] * D + lane * 2);
#pragma unroll
                for (int u = 0; u < 4; u++) { acc0 += (float)hv[u][0]; acc1 += (float)hv[u][1]; }
            }
            for (; j < mm; j++) {
                int s = __shfl(ep, j);
                bf16x2 hv = *(const bf16x2*)(Hs + (size_t)s * D + lane * 2);
                acc0 += (float)hv[0]; acc1 += (float)hv[1];
            }
        }

        acc0 = acc0 * di + b0;
        acc1 = acc1 * di + b1;
        acc0 = acc0 >= 0.f ? acc0 : 0.01f * acc0;
        acc1 = acc1 >= 0.f ? acc1 : 0.01f * acc1;
        bf16x2 o; o[0] = (__bf16)acc0; o[1] = (__bf16)acc1;
        *(bf16x2*)(O + (size_t)node * D + lane * 2) = o;
    }
}

// ---------------- pooling: per-graph-slice vectorized reduction + fused FC ----------------
__launch_bounds__(256)
__global__ void k_pool(const __bf16* __restrict__ H, const int* __restrict__ gstart,
                       float* __restrict__ pooled,
                       const float* __restrict__ fcW, const float* __restrict__ fcb,
                       float* __restrict__ out, int* __restrict__ done) {
    __shared__ float sdata[256 * 9];
    __shared__ int lastflag;
    int g = blockIdx.x / PSLICE;
    int slice = blockIdx.x - g * PSLICE;
    int gs = gstart[g], ge = gstart[g + 1];
    int cg = ge - gs;
    int r0 = gs + (int)((long long)cg * slice / PSLICE);
    int r1 = gs + (int)((long long)cg * (slice + 1) / PSLICE);
    int t = threadIdx.x;
    int rg = t >> 4, fb = t & 15;

    float acc[8];
#pragma unroll
    for (int j = 0; j < 8; j++) acc[j] = 0.f;
    for (int r = r0 + rg; r < r1; r += 16) {
        bf16x8 v = *(const bf16x8*)(H + (size_t)r * D + fb * 8);
#pragma unroll
        for (int j = 0; j < 8; j++) acc[j] += (float)v[j];
    }
#pragma unroll
    for (int j = 0; j < 8; j++) sdata[t * 9 + j] = acc[j];
    __syncthreads();
#pragma unroll
    for (int s = 128; s >= 16; s >>= 1) {
        if (t < s) {
#pragma unroll
            for (int j = 0; j < 8; j++) sdata[t * 9 + j] += sdata[(t + s) * 9 + j];
        }
        __syncthreads();
    }
    if (t < 16) {
#pragma unroll
        for (int j = 0; j < 8; j++) atomicAdd(&pooled[g * D + t * 8 + j], sdata[t * 9 + j]);
    }
    __threadfence();
    __syncthreads();
    if (t == 0) lastflag = (atomicAdd(done, 1) == (int)gridDim.x - 1) ? 1 : 0;
    __syncthreads();
    if (lastflag) {
        __threadfence();
        if (t < NUM_GRAPHS) {
            float s = 0.f;
#pragma unroll 4
            for (int k = 0; k < D; k++) s += pooled[t * D + k] * fcW[k];
            float c = (float)(gstart[t + 1] - gstart[t]);
            out[t] = s / fmaxf(c, 1.0f) + fcb[0];
        }
    }
}

extern "C" void kernel_launch(void* const* d_in, const int* in_sizes, int n_in,
                              void* d_out, int out_size, void* d_ws, size_t ws_size,
                              hipStream_t stream) {
    const float* x    = (const float*)d_in[0];
    const int*   ei   = (const int*)d_in[1];
    const int*   batch= (const int*)d_in[2];
    const float* W1   = (const float*)d_in[3];
    const float* b1   = (const float*)d_in[4];
    const float* W2   = (const float*)d_in[5];
    const float* b2   = (const float*)d_in[6];
    const float* fcW  = (const float*)d_in[7];
    const float* fcb  = (const float*)d_in[8];
    float* out = (float*)d_out;

    int N = in_sizes[0] / D;
    int E = in_sizes[1] / 2;

    int NBUCK  = (N + BUCK_N - 1) >> BUCK_SH;  // 391 for N=100000 (<=512)
    int NCHUNK = (E + CHUNK - 1) / CHUNK;      // 196 for E=1.6M
    int M = NBUCK * NCHUNK;                    // 76,636
    int mb = (M + 1023) / 1024;                // 75 (<=256)

    char* p = (char*)d_ws;
    auto alloc = [&](size_t bytes) { char* r = p; p += (bytes + 255) & ~(size_t)255; return r; };
    int*    cnt    = (int*)   alloc((size_t)N * 4);
    int*    offs   = (int*)   alloc((size_t)N * 4);
    int*    bsum2  = (int*)   alloc(256 * 4);
    float*  dis    = (float*) alloc((size_t)N * 4);
    int*    hist   = (int*)   alloc((size_t)M * 4);
    int*    histS  = (int*)   alloc((size_t)M * 4);
    int*    bbuf   = (int*)   alloc((size_t)E * 4);
    int*    esrc   = (int*)   alloc((size_t)E * 4);
    __bf16* bufA   = (__bf16*)alloc((size_t)N * D * 2);
    __bf16* bufB   = (__bf16*)alloc((size_t)N * D * 2);
    __bf16* Wf1    = (__bf16*)alloc((size_t)D * D * 2);
    __bf16* Wf2    = (__bf16*)alloc((size_t)D * D * 2);
    float*  pooled = (float*) alloc((size_t)NUM_GRAPHS * D * 4);
    int*    gstart = (int*)   alloc((NUM_GRAPHS + 1) * 4);
    int*    done   = (int*)   alloc(256);

    // CSR build: hist -> scan -> bin -> per-bucket place (all-LDS cursors)
    k_hist <<<NCHUNK, 256, 0, stream>>>(ei + E, hist, NBUCK, NCHUNK, E);
    k_scan1<<<mb, 256, 0, stream>>>(hist, histS, bsum2, M);
    k_scan2<<<1, 256, 0, stream>>>(bsum2, mb);
    k_bin  <<<NCHUNK, 256, 0, stream>>>(ei, histS, bsum2, bbuf, NBUCK, NCHUNK, E);
    k_place<<<NBUCK, 256, 0, stream>>>(bbuf, histS, bsum2, esrc, cnt, offs, dis,
                                       NBUCK, NCHUNK, N, E);

    k_prepW<<<129, 256, 0, stream>>>(W1, W2, Wf1, Wf2, pooled, done, batch, gstart, N);

    int gblocks = (N + 63) / 64;
    int ablocks = (N + 31) / 32;     // k_agg: 4 waves/block x 8 nodes/wave
    int fblocks = (N + 63) / 64;     // k_aggmm: 4 waves/block x 16 nodes/wave

    // layer 1 GEMM (prescaled by dis): bufA = dis .* (x @ W1)
    k_gemm<float><<<gblocks, 256, 0, stream>>>(x, Wf1, dis, bufA, N);
    // fused layer-1 agg + layer-2 GEMM: bufB = dis .* (leaky(agg(bufA)+b1) @ W2)
    k_aggmm<<<fblocks, 256, 0, stream>>>(bufA, Wf2, bufB, offs, cnt, dis, esrc, b1, N);
    // layer-2 agg: bufA = leaky(agg(bufB)+b2)
    k_agg<<<ablocks, 256, 0, stream>>>(bufB, bufA, offs, cnt, dis, esrc, b2, N);
    // pool (vectorized, per-graph slices) + fused fc
    k_pool<<<NUM_GRAPHS * PSLICE, 256, 0, stream>>>(bufA, gstart, pooled, fcW, fcb, out, done);
}

// Round 11
// 330.200 us; speedup vs baseline: 1.1195x; 1.1195x over previous
//
#include <hip/hip_runtime.h>
#include <hip/hip_bf16.h>
#include <math.h>

#define D 128
#define NUM_GRAPHS 64
#define CHUNK 8192          // edges per binning block
#define BUCK_SH 8           // bucket = col >> 8  (256 nodes per bucket)
#define BUCK_N 256
#define PSLICE 8            // pooling blocks per graph

typedef __bf16 bf16x8 __attribute__((ext_vector_type(8)));
typedef __bf16 bf16x2 __attribute__((ext_vector_type(2)));
typedef float f32x4 __attribute__((ext_vector_type(4)));
typedef float f32x2 __attribute__((ext_vector_type(2)));

// fp8 e4m3 (OCP) helpers — HW converts on gfx950
__device__ inline unsigned char f32_to_fp8(float x) {
    int pk = __builtin_amdgcn_cvt_pk_fp8_f32(x, x, 0, false);
    return (unsigned char)(pk & 0xff);
}
__device__ inline f32x2 fp8x2_to_f32(unsigned short us) {
    return __builtin_amdgcn_cvt_pk_f32_fp8((unsigned int)us, false);
}

// ---------------- generic scan helpers (for the bucket-chunk table) ----------------
__global__ void k_scan1(const int* __restrict__ in, int* __restrict__ outv,
                        int* __restrict__ bsum, int N) {
    __shared__ int lds[256];
    int t = threadIdx.x;
    int base = blockIdx.x * 1024 + t * 4;
    int v[4]; int local = 0;
#pragma unroll
    for (int j = 0; j < 4; j++) { v[j] = (base + j < N) ? in[base + j] : 0; local += v[j]; }
    lds[t] = local;
    __syncthreads();
    for (int off = 1; off < 256; off <<= 1) {
        int x = (t >= off) ? lds[t - off] : 0;
        __syncthreads();
        lds[t] += x;
        __syncthreads();
    }
    int excl = lds[t] - local;
    if (t == 255) bsum[blockIdx.x] = lds[255];
    int run = excl;
#pragma unroll
    for (int j = 0; j < 4; j++) { if (base + j < N) outv[base + j] = run; run += v[j]; }
}

__global__ void k_scan2(int* __restrict__ bsum, int nb) {
    __shared__ int lds[256];
    int t = threadIdx.x;
    int v = (t < nb) ? bsum[t] : 0;
    lds[t] = v;
    __syncthreads();
    for (int off = 1; off < 256; off <<= 1) {
        int x = (t >= off) ? lds[t - off] : 0;
        __syncthreads();
        lds[t] += x;
        __syncthreads();
    }
    if (t < nb) bsum[t] = lds[t] - v;
}

// ---------------- CSR build: two-level counting sort ----------------
__global__ void k_hist(const int* __restrict__ col, int* __restrict__ hist,
                       int nbuck, int nchunk, int E) {
    __shared__ int h[512];
    int tid = threadIdx.x;
    for (int b = tid; b < nbuck; b += 256) h[b] = 0;
    __syncthreads();
    int base = blockIdx.x * CHUNK;
    for (int i = tid; i < CHUNK; i += 256) {
        int e = base + i;
        if (e < E) atomicAdd(&h[col[e] >> BUCK_SH], 1);
    }
    __syncthreads();
    for (int b = tid; b < nbuck; b += 256) hist[b * nchunk + blockIdx.x] = h[b];
}

__global__ void k_bin(const int* __restrict__ ei, const int* __restrict__ histS,
                      const int* __restrict__ bsum2, int* __restrict__ bbuf,
                      int nbuck, int nchunk, int E) {
    __shared__ int cur[512];
    int tid = threadIdx.x;
    for (int b = tid; b < nbuck; b += 256) {
        int idx = b * nchunk + blockIdx.x;
        cur[b] = histS[idx] + bsum2[idx >> 10];
    }
    __syncthreads();
    int base = blockIdx.x * CHUNK;
    for (int i = tid; i < CHUNK; i += 256) {
        int e = base + i;
        if (e < E) {
            int r = ei[e], c = ei[E + e];
            int pos = atomicAdd(&cur[c >> BUCK_SH], 1);
            bbuf[pos] = r | ((c & (BUCK_N - 1)) << 17);   // src fits 17 bits (N < 131072)
        }
    }
}

// per-bucket exact CSR: LDS histogram + LDS scan + LDS cursors. No global atomics.
__global__ void k_place(const int* __restrict__ bbuf, const int* __restrict__ histS,
                        const int* __restrict__ bsum2, int* __restrict__ esrc,
                        int* __restrict__ cnt, int* __restrict__ offs,
                        float* __restrict__ dis,
                        int nbuck, int nchunk, int N, int E) {
    __shared__ int h[256];
    __shared__ int sc[256];
    __shared__ int cur[256];
    int b = blockIdx.x, tid = threadIdx.x;
    int i0 = b * nchunk;
    int start = histS[i0] + bsum2[i0 >> 10];
    int end = E;
    if (b + 1 < nbuck) { int i1 = (b + 1) * nchunk; end = histS[i1] + bsum2[i1 >> 10]; }
    h[tid] = 0;
    __syncthreads();
    for (int i = start + tid; i < end; i += 256) atomicAdd(&h[(bbuf[i] >> 17) & 255], 1);
    __syncthreads();
    int local = h[tid];
    sc[tid] = local;
    __syncthreads();
    for (int off = 1; off < 256; off <<= 1) {
        int xv = (tid >= off) ? sc[tid - off] : 0;
        __syncthreads();
        sc[tid] += xv;
        __syncthreads();
    }
    int excl = sc[tid] - local;
    cur[tid] = start + excl;
    int c = b * 256 + tid;
    if (c < N) {
        cnt[c]  = local;
        offs[c] = start + excl;
        dis[c]  = rsqrtf(1.0f + (float)local);   // deg includes self-loop
    }
    __syncthreads();
    for (int i = start + tid; i < end; i += 256) {
        int p = bbuf[i];
        int pos = atomicAdd(&cur[(p >> 17) & 255], 1);
        esrc[pos] = p & 0x1FFFF;
    }
}

// ---------------- W -> bf16 B-fragment pack; zero pooled/done; graph boundaries ----------------
__global__ void k_prepW(const float* __restrict__ Wa, const float* __restrict__ Wb,
                        __bf16* __restrict__ WfA, __bf16* __restrict__ WfB,
                        float* __restrict__ pooled, int* __restrict__ done,
                        const int* __restrict__ batch, int* __restrict__ gstart, int N) {
    int gid = blockIdx.x * 256 + threadIdx.x;   // 0..32767
    if (gid < NUM_GRAPHS * D) pooled[gid] = 0.f;
    if (gid == 0) *done = 0;
    if (gid >= 16384 && gid <= 16384 + NUM_GRAPHS) {   // 65 threads do binary search
        int g = gid - 16384;
        int lo = 0, hi = N;
        while (lo < hi) { int mid = (lo + hi) >> 1; if (batch[mid] < g) lo = mid + 1; else hi = mid; }
        gstart[g] = lo;
    }
    const float* W = (gid < 16384) ? Wa : Wb;
    __bf16* Wf = (gid < 16384) ? WfA : WfB;
    int idx = gid & 16383;
    int j = idx & 7, lane = (idx >> 3) & 63, kc = (idx >> 9) & 3, ft = idx >> 11;
    int k = kc * 32 + (lane >> 4) * 8 + j;
    int f = ft * 16 + (lane & 15);
    Wf[idx] = (__bf16)W[k * D + f];
}

// ---------------- MFMA GEMM: Y8[N,128](fp8) = dis .* (X[N,128] @ W) ----------------
// fp8 output: halves the downstream gather bytes. Accumulation fp32, one
// rounding point to fp8 e4m3 in the epilogue.
template <typename T>
__launch_bounds__(256)
__global__ void k_gemm(const T* __restrict__ X, const __bf16* __restrict__ Wfrag,
                       const float* __restrict__ dis, unsigned char* __restrict__ Y8, int N) {
    int tid = threadIdx.x;
    int w = tid >> 6, lane = tid & 63;
    int quad = lane >> 4, m = lane & 15;
    int nodeA = blockIdx.x * 64 + w * 16 + m;
    if (nodeA >= N) nodeA = N - 1;

    bf16x8 a[4];
#pragma unroll
    for (int kc = 0; kc < 4; kc++) {
        int kb = kc * 32 + quad * 8;
        if constexpr (sizeof(T) == 4) {
            f32x4 x0 = *(const f32x4*)(X + (size_t)nodeA * D + kb);
            f32x4 x1 = *(const f32x4*)(X + (size_t)nodeA * D + kb + 4);
#pragma unroll
            for (int j = 0; j < 4; j++) { a[kc][j] = (__bf16)x0[j]; a[kc][4 + j] = (__bf16)x1[j]; }
        } else {
            a[kc] = *(const bf16x8*)(X + (size_t)nodeA * D + kb);
        }
    }

    f32x4 d[8];
#pragma unroll
    for (int ft = 0; ft < 8; ft++) {
        d[ft] = (f32x4){0.f, 0.f, 0.f, 0.f};
#pragma unroll
        for (int kc = 0; kc < 4; kc++) {
            bf16x8 b = *(const bf16x8*)(Wfrag + (((ft << 2) | kc) * 64 + lane) * 8);
            d[ft] = __builtin_amdgcn_mfma_f32_16x16x32_bf16(a[kc], b, d[ft], 0, 0, 0);
        }
    }

#pragma unroll
    for (int r = 0; r < 4; r++) {
        int node = blockIdx.x * 64 + w * 16 + quad * 4 + r;
        if (node < N) {
            float dv = dis[node];
#pragma unroll
            for (int ft = 0; ft < 8; ft++)
                Y8[(size_t)node * D + ft * 16 + m] = f32_to_fp8(d[ft][r] * dv);
        }
    }
}

// ---------------- CSR aggregation + bias + leaky ReLU (fp8 in, bf16 out) ----------------
// Hs8 prescaled by dis -> no per-edge weight. One wave per 8 consecutive nodes.
// Lane owns feats (2*lane, 2*lane+1) = one ushort (2 fp8) per row -> a wave
// gathers a full 128B row coalesced. fp32 accumulate; HW pk-cvt per element pair.
__launch_bounds__(256)
__global__ void k_agg(const unsigned char* __restrict__ Hs8, __bf16* __restrict__ O,
                      const int* __restrict__ offs, const int* __restrict__ cnt,
                      const float* __restrict__ dis, const int* __restrict__ esrc,
                      const float* __restrict__ bias, int N) {
    int wave = (blockIdx.x * 256 + threadIdx.x) >> 6;
    int lane = threadIdx.x & 63;
    int node0 = wave * 8;
    float b0 = bias[lane * 2], b1 = bias[lane * 2 + 1];

    for (int nn = 0; nn < 8; nn++) {
        int node = node0 + nn;
        if (node >= N) return;
        int start = offs[node];
        int len = cnt[node];
        float di = dis[node];
        f32x2 h = fp8x2_to_f32(*(const unsigned short*)(Hs8 + (size_t)node * D + lane * 2));
        float acc0 = h[0];               // self-loop term (already dis-scaled)
        float acc1 = h[1];

        for (int k0 = 0; k0 < len; k0 += 64) {
            int mm = len - k0; if (mm > 64) mm = 64;
            int ep = esrc[start + k0 + (lane < mm ? lane : 0)];
            int j = 0;
            for (; j + 16 <= mm; j += 16) {
                int s[16]; unsigned short hv[16];
#pragma unroll
                for (int u = 0; u < 16; u++) s[u] = __shfl(ep, j + u);
#pragma unroll
                for (int u = 0; u < 16; u++) hv[u] = *(const unsigned short*)(Hs8 + (size_t)s[u] * D + lane * 2);
#pragma unroll
                for (int u = 0; u < 16; u++) { f32x2 f = fp8x2_to_f32(hv[u]); acc0 += f[0]; acc1 += f[1]; }
            }
            for (; j + 4 <= mm; j += 4) {
                int s[4]; unsigned short hv[4];
#pragma unroll
                for (int u = 0; u < 4; u++) s[u] = __shfl(ep, j + u);
#pragma unroll
                for (int u = 0; u < 4; u++) hv[u] = *(const unsigned short*)(Hs8 + (size_t)s[u] * D + lane * 2);
#pragma unroll
                for (int u = 0; u < 4; u++) { f32x2 f = fp8x2_to_f32(hv[u]); acc0 += f[0]; acc1 += f[1]; }
            }
            for (; j < mm; j++) {
                int s = __shfl(ep, j);
                f32x2 f = fp8x2_to_f32(*(const unsigned short*)(Hs8 + (size_t)s * D + lane * 2));
                acc0 += f[0]; acc1 += f[1];
            }
        }

        acc0 = acc0 * di + b0;
        acc1 = acc1 * di + b1;
        acc0 = acc0 >= 0.f ? acc0 : 0.01f * acc0;
        acc1 = acc1 >= 0.f ? acc1 : 0.01f * acc1;
        bf16x2 o; o[0] = (__bf16)acc0; o[1] = (__bf16)acc1;
        *(bf16x2*)(O + (size_t)node * D + lane * 2) = o;
    }
}

// ---------------- pooling: per-graph-slice vectorized reduction + fused FC ----------------
__launch_bounds__(256)
__global__ void k_pool(const __bf16* __restrict__ H, const int* __restrict__ gstart,
                       float* __restrict__ pooled,
                       const float* __restrict__ fcW, const float* __restrict__ fcb,
                       float* __restrict__ out, int* __restrict__ done) {
    __shared__ float sdata[256 * 9];
    __shared__ int lastflag;
    int g = blockIdx.x / PSLICE;
    int slice = blockIdx.x - g * PSLICE;
    int gs = gstart[g], ge = gstart[g + 1];
    int cg = ge - gs;
    int r0 = gs + (int)((long long)cg * slice / PSLICE);
    int r1 = gs + (int)((long long)cg * (slice + 1) / PSLICE);
    int t = threadIdx.x;
    int rg = t >> 4, fb = t & 15;

    float acc[8];
#pragma unroll
    for (int j = 0; j < 8; j++) acc[j] = 0.f;
    for (int r = r0 + rg; r < r1; r += 16) {
        bf16x8 v = *(const bf16x8*)(H + (size_t)r * D + fb * 8);
#pragma unroll
        for (int j = 0; j < 8; j++) acc[j] += (float)v[j];
    }
#pragma unroll
    for (int j = 0; j < 8; j++) sdata[t * 9 + j] = acc[j];
    __syncthreads();
#pragma unroll
    for (int s = 128; s >= 16; s >>= 1) {
        if (t < s) {
#pragma unroll
            for (int j = 0; j < 8; j++) sdata[t * 9 + j] += sdata[(t + s) * 9 + j];
        }
        __syncthreads();
    }
    if (t < 16) {
#pragma unroll
        for (int j = 0; j < 8; j++) atomicAdd(&pooled[g * D + t * 8 + j], sdata[t * 9 + j]);
    }
    __threadfence();
    __syncthreads();
    if (t == 0) lastflag = (atomicAdd(done, 1) == (int)gridDim.x - 1) ? 1 : 0;
    __syncthreads();
    if (lastflag) {
        __threadfence();
        if (t < NUM_GRAPHS) {
            float s = 0.f;
#pragma unroll 4
            for (int k = 0; k < D; k++) s += pooled[t * D + k] * fcW[k];
            float c = (float)(gstart[t + 1] - gstart[t]);
            out[t] = s / fmaxf(c, 1.0f) + fcb[0];
        }
    }
}

extern "C" void kernel_launch(void* const* d_in, const int* in_sizes, int n_in,
                              void* d_out, int out_size, void* d_ws, size_t ws_size,
                              hipStream_t stream) {
    const float* x    = (const float*)d_in[0];
    const int*   ei   = (const int*)d_in[1];
    const int*   batch= (const int*)d_in[2];
    const float* W1   = (const float*)d_in[3];
    const float* b1   = (const float*)d_in[4];
    const float* W2   = (const float*)d_in[5];
    const float* b2   = (const float*)d_in[6];
    const float* fcW  = (const float*)d_in[7];
    const float* fcb  = (const float*)d_in[8];
    float* out = (float*)d_out;

    int N = in_sizes[0] / D;
    int E = in_sizes[1] / 2;

    int NBUCK  = (N + BUCK_N - 1) >> BUCK_SH;  // 391 for N=100000 (<=512)
    int NCHUNK = (E + CHUNK - 1) / CHUNK;      // 196 for E=1.6M
    int M = NBUCK * NCHUNK;                    // 76,636
    int mb = (M + 1023) / 1024;                // 75 (<=256)

    char* p = (char*)d_ws;
    auto alloc = [&](size_t bytes) { char* r = p; p += (bytes + 255) & ~(size_t)255; return r; };
    int*    cnt    = (int*)   alloc((size_t)N * 4);
    int*    offs   = (int*)   alloc((size_t)N * 4);
    int*    bsum2  = (int*)   alloc(256 * 4);
    float*  dis    = (float*) alloc((size_t)N * 4);
    int*    hist   = (int*)   alloc((size_t)M * 4);
    int*    histS  = (int*)   alloc((size_t)M * 4);
    int*    bbuf   = (int*)   alloc((size_t)E * 4);
    int*    esrc   = (int*)   alloc((size_t)E * 4);
    unsigned char* bufA8 = (unsigned char*)alloc((size_t)N * D);   // fp8 messages
    __bf16* bufB   = (__bf16*)alloc((size_t)N * D * 2);
    __bf16* Wf1    = (__bf16*)alloc((size_t)D * D * 2);
    __bf16* Wf2    = (__bf16*)alloc((size_t)D * D * 2);
    float*  pooled = (float*) alloc((size_t)NUM_GRAPHS * D * 4);
    int*    gstart = (int*)   alloc((NUM_GRAPHS + 1) * 4);
    int*    done   = (int*)   alloc(256);

    // CSR build: hist -> scan -> bin -> per-bucket place (all-LDS cursors)
    k_hist <<<NCHUNK, 256, 0, stream>>>(ei + E, hist, NBUCK, NCHUNK, E);
    k_scan1<<<mb, 256, 0, stream>>>(hist, histS, bsum2, M);
    k_scan2<<<1, 256, 0, stream>>>(bsum2, mb);
    k_bin  <<<NCHUNK, 256, 0, stream>>>(ei, histS, bsum2, bbuf, NBUCK, NCHUNK, E);
    k_place<<<NBUCK, 256, 0, stream>>>(bbuf, histS, bsum2, esrc, cnt, offs, dis,
                                       NBUCK, NCHUNK, N, E);

    k_prepW<<<129, 256, 0, stream>>>(W1, W2, Wf1, Wf2, pooled, done, batch, gstart, N);

    int gblocks = (N + 63) / 64;
    int ablocks = (N + 31) / 32;     // k_agg: 4 waves/block x 8 nodes/wave

    // layer 1: bufA8 = fp8(dis .* (x @ W1)); bufB = leaky(agg(bufA8)+b1)
    k_gemm<float><<<gblocks, 256, 0, stream>>>(x, Wf1, dis, bufA8, N);
    k_agg<<<ablocks, 256, 0, stream>>>(bufA8, bufB, offs, cnt, dis, esrc, b1, N);
    // layer 2: bufA8 = fp8(dis .* (bufB @ W2)); bufB = leaky(agg(bufA8)+b2)
    k_gemm<__bf16><<<gblocks, 256, 0, stream>>>(bufB, Wf2, dis, bufA8, N);
    k_agg<<<ablocks, 256, 0, stream>>>(bufA8, bufB, offs, cnt, dis, esrc, b2, N);
    // pool (vectorized, per-graph slices) + fused fc
    k_pool<<<NUM_GRAPHS * PSLICE, 256, 0, stream>>>(bufB, gstart, pooled, fcW, fcb, out, done);
}